// Round 1
// baseline (1698.962 us; speedup 1.0000x reference)
//
#include <hip/hip_runtime.h>
#include <math.h>

typedef unsigned int u32;
typedef unsigned short u16;
typedef __attribute__((ext_vector_type(8))) short short8;
typedef __attribute__((ext_vector_type(4))) float f32x4;

// Problem constants (ExpertChoiceRouter: B=8, S=4096, D=4096, H=D/4=1024)
constexpr int BB = 8;
constexpr int S  = 4096;
constexpr int D  = 4096;
constexpr int H  = 1024;
constexpr int M  = BB * S;        // 32768 rows
constexpr int BM = 128;
constexpr int BN = 64;
constexpr int BK = 32;
constexpr int NT     = H / BN;    // 16 n-tiles
constexpr int MTILES = M / BM;    // 256 m-tiles
constexpr int KSTEPS = D / BK;    // 128

// d_ws layout:
//   part  : [NT][M] float          @ 0        (2 MB)
//   Bp_hi : [NT*KSTEPS][4][64][8] bf16 @ 2 MB  (8 MB)
//   Bp_lo : same                   @ 10 MB    (8 MB)

// --- split fp32 -> bf16 hi (truncate) + bf16 lo (residual, truncate) -------
__device__ inline void split_bf16(float x, u16& h, u16& l) {
    u32 u  = __float_as_uint(x);
    u32 hu = u & 0xFFFF0000u;
    h = (u16)(u >> 16);
    float r = x - __uint_as_float(hu);      // exact (Sterbenz)
    l = (u16)(__float_as_uint(r) >> 16);
}

__device__ inline f32x4 mfma16(short8 a, short8 b, f32x4 c) {
    return __builtin_amdgcn_mfma_f32_16x16x32_bf16(a, b, c, 0, 0, 0);
}

__device__ inline void gl_lds16(const u16* g, u16* l) {
    __builtin_amdgcn_global_load_lds(
        (const __attribute__((address_space(1))) u32*)g,
        (__attribute__((address_space(3))) u32*)l, 16, 0, 0);
}

// ---------------------------------------------------------------------------
// Pack W1 (fp32 [D][H]) -> Bp_hi/Bp_lo bf16 in MFMA B-fragment order:
// Bp[nt*128+ks][k8][n][j] = W1[ks*32+k8*8+j][nt*64+n]  (j contiguous => b128 frag)
// ---------------------------------------------------------------------------
__global__ __launch_bounds__(256) void pack_w1(
    const float* __restrict__ W1, u16* __restrict__ bh, u16* __restrict__ bl)
{
    int blk = blockIdx.x;              // nt*128 + ks
    int nt = blk >> 7, ks = blk & 127;
    int t  = threadIdx.x;
    int k8 = t >> 6, n = t & 63;
    int kbase = ks * 32 + k8 * 8;

    short8 vh, vl;
    #pragma unroll
    for (int j = 0; j < 8; ++j) {
        float x = W1[(size_t)(kbase + j) * H + nt * 64 + n];
        u16 hh, ll;
        split_bf16(x, hh, ll);
        vh[j] = (short)hh;
        vl[j] = (short)ll;
    }
    size_t base = (size_t)blk * 2048 + k8 * 512 + n * 8;
    *reinterpret_cast<short8*>(bh + base) = vh;
    *reinterpret_cast<short8*>(bl + base) = vl;
}

// ---------------------------------------------------------------------------
// MFMA GEMM v2: software-pipelined (prefetch-compute-barrier).
//   - B tile: double-buffered LDS via global_load_lds
//   - A tile: double-buffered registers (raw fp32 loads, split in-loop)
//   - ONE __syncthreads per K-step; its vmcnt drain lands AFTER the MFMAs,
//     so next-step load latency hides under current-step compute.
// Fused +b1 / exact-GELU / *W2 epilogue writes per-n-tile partials part[nt][m].
// ---------------------------------------------------------------------------
struct Areg { f32x4 a0lo, a0hi, a1lo, a1hi; };

__device__ inline void loadA(const float* p0, const float* p1, int k, Areg& r) {
    const float* q0 = p0 + k * BK;
    const float* q1 = p1 + k * BK;
    r.a0lo = *(const f32x4*)(q0);
    r.a0hi = *(const f32x4*)(q0 + 4);
    r.a1lo = *(const f32x4*)(q1);
    r.a1hi = *(const f32x4*)(q1 + 4);
}

__device__ inline void stageB(const u16* gsrc, u16* lbase, int nt, int k, int lane) {
    const u16* g0 = gsrc + (size_t)(nt * 128 + k) * 2048 + lane * 8;
    gl_lds16(g0,       lbase + lane * 8);
    gl_lds16(g0 + 512, lbase + 512 + lane * 8);
}

__device__ inline void computeStep(const Areg& ar, const u16* BhBuf, const u16* BlBuf,
                                   int quad, int li, f32x4 acc[2][4]) {
    short8 ah[2], al[2];
    #pragma unroll
    for (int e = 0; e < 4; ++e) {
        u16 h, l;
        split_bf16(ar.a0lo[e], h, l); ah[0][e]     = (short)h; al[0][e]     = (short)l;
        split_bf16(ar.a0hi[e], h, l); ah[0][e + 4] = (short)h; al[0][e + 4] = (short)l;
        split_bf16(ar.a1lo[e], h, l); ah[1][e]     = (short)h; al[1][e]     = (short)l;
        split_bf16(ar.a1hi[e], h, l); ah[1][e + 4] = (short)h; al[1][e + 4] = (short)l;
    }
    #pragma unroll
    for (int ntl = 0; ntl < 4; ++ntl) {
        int off = (quad * 64 + ntl * 16 + li) * 8;
        short8 bhf = *reinterpret_cast<const short8*>(BhBuf + off);
        short8 blf = *reinterpret_cast<const short8*>(BlBuf + off);
        #pragma unroll
        for (int mtl = 0; mtl < 2; ++mtl) {
            acc[mtl][ntl] = mfma16(ah[mtl], bhf, acc[mtl][ntl]);
            acc[mtl][ntl] = mfma16(al[mtl], bhf, acc[mtl][ntl]);
            acc[mtl][ntl] = mfma16(ah[mtl], blf, acc[mtl][ntl]);
        }
    }
}

__global__ __launch_bounds__(256, 4) void gemm_mfma(
    const float* __restrict__ X,
    const u16*   __restrict__ Bph, const u16* __restrict__ Bpl,
    const float* __restrict__ b1,  const float* __restrict__ W2,
    float*       __restrict__ part)
{
    __shared__ u16 Bh[2][4 * 64 * 8];   // [buf][k8][n][8]  4 KB each
    __shared__ u16 Bl[2][4 * 64 * 8];

    // XCD swizzle: 16 n-tiles of one m-stripe land on one XCD (X read ~once).
    int b   = blockIdx.x;
    int xcd = b & 7;
    int j   = b >> 3;
    int nt  = j & 15;
    int mtg = j >> 4;
    int mt  = mtg * 8 + xcd;
    int m0  = mt * BM;
    int n0  = nt * BN;

    int tid  = threadIdx.x;
    int lane = tid & 63, wv = tid >> 6;
    int li   = lane & 15, quad = lane >> 4;

    // A pointers: lane loads rows m0 + wv*32 + mtl*16 + li, k = ks*32 + quad*8 ..
    const float* aptr0 = X + (size_t)(m0 + wv * 32 +  0 + li) * D + quad * 8;
    const float* aptr1 = X + (size_t)(m0 + wv * 32 + 16 + li) * D + quad * 8;

    // B staging assignment: waves 0,1 -> hi halves; waves 2,3 -> lo halves
    const u16* gsrc = (wv < 2) ? Bph : Bpl;
    int wvh = (wv & 1) * 1024;
    u16* lb0 = ((wv < 2) ? Bh[0] : Bl[0]) + wvh;
    u16* lb1 = ((wv < 2) ? Bh[1] : Bl[1]) + wvh;
    const u16* gbase = gsrc + wvh;   // stage half-tile: + (wv&1)*1024 within step

    f32x4 acc[2][4] = {};
    Areg rA, rB;

    // ---- prologue: stage step 0 into buf0, load A(0) ----
    stageB(gbase, lb0, nt, 0, lane);
    loadA(aptr0, aptr1, 0, rA);
    __syncthreads();

    for (int ks = 0; ks < KSTEPS; ks += 2) {
        int k1 = ks + 1;                                   // always < KSTEPS
        int k2 = (ks + 2 < KSTEPS) ? ks + 2 : KSTEPS - 1;  // clamp (last iter redundant)

        // ---- phase A: prefetch k1 -> {buf1, rB}; compute ks from {buf0, rA} ----
        stageB(gbase, lb1, nt, k1, lane);
        loadA(aptr0, aptr1, k1, rB);
        computeStep(rA, Bh[0], Bl[0], quad, li, acc);
        __syncthreads();   // drains vmcnt: buf1 + rB ready for next phase

        // ---- phase B: prefetch k2 -> {buf0, rA}; compute k1 from {buf1, rB} ----
        stageB(gbase, lb0, nt, k2, lane);
        loadA(aptr0, aptr1, k2, rA);
        computeStep(rB, Bh[1], Bl[1], quad, li, acc);
        __syncthreads();   // drains vmcnt: buf0 + rA ready
    }

    // ---- epilogue: +b1, exact GELU, *W2, reduce over this 64-wide n-slice ----
    float b1v[4], w2v[4];
    #pragma unroll
    for (int ntl = 0; ntl < 4; ++ntl) {
        b1v[ntl] = b1[n0 + ntl * 16 + li];
        w2v[ntl] = W2[n0 + ntl * 16 + li];
    }
    #pragma unroll
    for (int mtl = 0; mtl < 2; ++mtl) {
        #pragma unroll
        for (int r = 0; r < 4; ++r) {
            float s = 0.f;
            #pragma unroll
            for (int ntl = 0; ntl < 4; ++ntl) {
                float x = acc[mtl][ntl][r] + b1v[ntl];
                float g = 0.5f * x * (1.0f + erff(x * 0.70710678118654752f));
                s += g * w2v[ntl];
            }
            // reduce across the 16 lanes (li) of this quad
            s += __shfl_xor(s, 1, 64);
            s += __shfl_xor(s, 2, 64);
            s += __shfl_xor(s, 4, 64);
            s += __shfl_xor(s, 8, 64);
            if (li == 0) {
                int row = m0 + wv * 32 + mtl * 16 + quad * 4 + r;
                part[(size_t)nt * M + row] = s;
            }
        }
    }
}

// ---------------------------------------------------------------------------
// Kernel B: per batch-row — reduce partials, sigmoid, variable-k selection
// via binary search over float-bit ordering.  (unchanged, verified)
// ---------------------------------------------------------------------------
__global__ __launch_bounds__(256) void select_topk(
    const float* __restrict__ part,  // [NT, M]
    const int*   __restrict__ mask,  // [BB, S] int32 (0/1)
    const float* __restrict__ b2,    // [1]
    float*       __restrict__ out)   // [2, BB, S]: weights then mask
{
    __shared__ unsigned us[S];
    __shared__ int      na_s, cnt_s, cgt_s, cge_s;
    __shared__ unsigned lo_s, hi_s;

    int brow = blockIdx.x;
    int tid  = threadIdx.x;

    if (tid == 0) na_s = 0;
    __syncthreads();

    float b2v = b2[0];
    int local_na = 0;
    for (int s = tid; s < S; s += 256) {
        float sum = 0.f;
        #pragma unroll
        for (int t = 0; t < NT; ++t) sum += part[t * M + brow * S + s];
        float logit = sum + b2v;
        float sc = 1.0f / (1.0f + expf(-logit));
        int a = mask[brow * S + s];
        us[s] = a ? __float_as_uint(sc) : 0u;
        local_na += (a ? 1 : 0);
    }
    atomicAdd(&na_s, local_na);
    __syncthreads();

    int n_act = na_s;
    int k = (n_act >= 1) ? max(n_act >> 1, 1) : 0;

    unsigned T = 0;
    if (k > 0) {
        if (tid == 0) { lo_s = 1u; hi_s = 0x3F800000u; }
        __syncthreads();
        while (true) {
            unsigned lo = lo_s, hi = hi_s;
            if (lo >= hi) break;
            unsigned mid = lo + ((hi - lo + 1u) >> 1);
            int local = 0;
            for (int s = tid; s < S; s += 256) local += (us[s] >= mid) ? 1 : 0;
            if (tid == 0) cnt_s = 0;
            __syncthreads();
            #pragma unroll
            for (int off = 32; off > 0; off >>= 1)
                local += __shfl_down(local, off, 64);
            if ((tid & 63) == 0) atomicAdd(&cnt_s, local);
            __syncthreads();
            int c = cnt_s;
            if (tid == 0) { if (c >= k) lo_s = mid; else hi_s = mid - 1u; }
            __syncthreads();
        }
        T = lo_s;

        int lgt = 0, lge = 0;
        for (int s = tid; s < S; s += 256) {
            lgt += (us[s] > T) ? 1 : 0;
            lge += (us[s] >= T) ? 1 : 0;
        }
        if (tid == 0) { cgt_s = 0; cge_s = 0; }
        __syncthreads();
        #pragma unroll
        for (int off = 32; off > 0; off >>= 1) {
            lgt += __shfl_down(lgt, off, 64);
            lge += __shfl_down(lge, off, 64);
        }
        if ((tid & 63) == 0) { atomicAdd(&cgt_s, lgt); atomicAdd(&cge_s, lge); }
        __syncthreads();
        int c_gt = cgt_s, c_ge = cge_s;
        int need_eq = k - c_gt;
        if (c_ge - c_gt != need_eq) {
            if (tid == 0) {
                int taken = 0;
                for (int s = 0; s < S; ++s) {
                    if (us[s] == T) {
                        if (taken >= need_eq) us[s] = 0u;
                        ++taken;
                    }
                }
            }
            __syncthreads();
        }
    }
    __syncthreads();

    for (int s = tid; s < S; s += 256) {
        bool sel = (k > 0) && (us[s] >= T);
        float sc = __uint_as_float(us[s]);
        out[brow * S + s]     = sel ? sc : 0.0f;
        out[M + brow * S + s] = sel ? 1.0f : 0.0f;
    }
}

// ---------------------------------------------------------------------------
extern "C" void kernel_launch(void* const* d_in, const int* in_sizes, int n_in,
                              void* d_out, int out_size, void* d_ws, size_t ws_size,
                              hipStream_t stream)
{
    const float* X    = (const float*)d_in[0];  // hidden_states [8,4096,4096]
    const int*   mask = (const int*)  d_in[1];  // active_mask   [8,4096]
    const float* W1   = (const float*)d_in[2];  // [4096,1024]
    const float* b1   = (const float*)d_in[3];  // [1024]
    const float* W2   = (const float*)d_in[4];  // [1024,1]
    const float* b2   = (const float*)d_in[5];  // [1]
    float* out  = (float*)d_out;                // [2, 8, 4096]

    float* part = (float*)d_ws;                           // 2 MB
    u16*   Bph  = (u16*)((char*)d_ws + (2u  << 20));      // 8 MB
    u16*   Bpl  = (u16*)((char*)d_ws + (10u << 20));      // 8 MB

    hipLaunchKernelGGL(pack_w1,   dim3(NT * KSTEPS),   dim3(256), 0, stream, W1, Bph, Bpl);
    hipLaunchKernelGGL(gemm_mfma, dim3(MTILES * NT),   dim3(256), 0, stream,
                       X, Bph, Bpl, b1, W2, part);
    hipLaunchKernelGGL(select_topk, dim3(BB), dim3(256), 0, stream, part, mask, b2, out);
}

// Round 2
// 1299.796 us; speedup vs baseline: 1.3071x; 1.3071x over previous
//
#include <hip/hip_runtime.h>
#include <math.h>

typedef unsigned int u32;
typedef unsigned short u16;
typedef __attribute__((ext_vector_type(8))) short short8;
typedef __attribute__((ext_vector_type(4))) float f32x4;

// Problem constants (ExpertChoiceRouter: B=8, S=4096, D=4096, H=D/4=1024)
constexpr int BB = 8;
constexpr int S  = 4096;
constexpr int D  = 4096;
constexpr int H  = 1024;
constexpr int M  = BB * S;        // 32768 rows
constexpr int BM = 128;
constexpr int BN = 256;           // widened: amortize A-split VALU over 4x MFMA
constexpr int BK = 32;
constexpr int NTB    = H / BN;    // 4 n-blocks
constexpr int MTILES = M / BM;    // 256 m-tiles
constexpr int KSTEPS = D / BK;    // 128
constexpr int CHUNK  = 4 * BN * 8; // u16 per (ntb,ks) B-chunk = 8192 (16 KB)

// d_ws layout:
//   part  : [NTB][M] float         @ 0      (512 KB, 2 MB reserved)
//   Bp_hi : [NTB*KSTEPS][4][256][8] bf16 @ 2 MB  (8 MB)
//   Bp_lo : same                   @ 10 MB  (8 MB)

// --- split fp32 -> bf16 hi (truncate) + bf16 lo (residual, truncate) -------
__device__ inline void split_bf16(float x, u16& h, u16& l) {
    u32 u  = __float_as_uint(x);
    u32 hu = u & 0xFFFF0000u;
    h = (u16)(u >> 16);
    float r = x - __uint_as_float(hu);      // exact (Sterbenz)
    l = (u16)(__float_as_uint(r) >> 16);
}

__device__ inline f32x4 mfma16(short8 a, short8 b, f32x4 c) {
    return __builtin_amdgcn_mfma_f32_16x16x32_bf16(a, b, c, 0, 0, 0);
}

__device__ inline void gl_lds16(const u16* g, u16* l) {
    __builtin_amdgcn_global_load_lds(
        (const __attribute__((address_space(1))) u32*)g,
        (__attribute__((address_space(3))) u32*)l, 16, 0, 0);
}

// ---------------------------------------------------------------------------
// Pack W1 (fp32 [D][H]) -> Bp_hi/Bp_lo bf16 in MFMA B-fragment order:
// Bp[(ntb*128+ks)][k8][n(256)][j(8)] = W1[ks*32+k8*8+j][ntb*256+n]
// ---------------------------------------------------------------------------
__global__ __launch_bounds__(1024) void pack_w1(
    const float* __restrict__ W1, u16* __restrict__ bh, u16* __restrict__ bl)
{
    int blk = blockIdx.x;              // ntb*128 + ks
    int ntb = blk >> 7, ks = blk & 127;
    int t  = threadIdx.x;              // 0..1023
    int k8 = t >> 8, n = t & 255;
    int kbase = ks * 32 + k8 * 8;

    short8 vh, vl;
    #pragma unroll
    for (int j = 0; j < 8; ++j) {
        float x = W1[(size_t)(kbase + j) * H + ntb * 256 + n];
        u16 hh, ll;
        split_bf16(x, hh, ll);
        vh[j] = (short)hh;
        vl[j] = (short)ll;
    }
    size_t base = (size_t)blk * CHUNK + k8 * 2048 + n * 8;
    *reinterpret_cast<short8*>(bh + base) = vh;
    *reinterpret_cast<short8*>(bl + base) = vl;
}

// ---------------------------------------------------------------------------
// MFMA GEMM v3: 128x256 block tile, 4 waves (each 32 rows x 256 cols).
// Per K-step per wave: 96 MFMAs (~480 cyc) vs ~160 cyc split VALU -> the
// A-split and the 2 barriers/step are amortized 4x better than v2.
// B double-buffered LDS via global_load_lds; A double-buffered in registers.
// ---------------------------------------------------------------------------
struct Areg { f32x4 a0lo, a0hi, a1lo, a1hi; };

__device__ inline void loadA(const float* p0, const float* p1, int k, Areg& r) {
    const float* q0 = p0 + k * BK;
    const float* q1 = p1 + k * BK;
    r.a0lo = *(const f32x4*)(q0);
    r.a0hi = *(const f32x4*)(q0 + 4);
    r.a1lo = *(const f32x4*)(q1);
    r.a1hi = *(const f32x4*)(q1 + 4);
}

__global__ __launch_bounds__(256, 2) void gemm_mfma(
    const float* __restrict__ X,
    const u16*   __restrict__ Bph, const u16* __restrict__ Bpl,
    const float* __restrict__ b1,  const float* __restrict__ W2,
    float*       __restrict__ part)
{
    __shared__ u16 Bh[2][CHUNK];   // [buf][k8][n][8]  16 KB each
    __shared__ u16 Bl[2][CHUNK];

    // XCD swizzle: 4 n-blocks of one m-stripe land on one XCD (X stripe in L2).
    int b   = blockIdx.x;
    int xcd = b & 7;
    int j   = b >> 3;
    int ntb = j & 3;
    int mtg = j >> 2;
    int mt  = mtg * 8 + xcd;
    int m0  = mt * BM;
    int n0  = ntb * BN;

    int tid  = threadIdx.x;
    int lane = tid & 63, wv = tid >> 6;
    int li   = lane & 15, quad = lane >> 4;

    // A pointers: lane loads rows m0 + wv*32 + {0,16} + li, k = ks*32 + quad*8 ..
    const float* aptr0 = X + (size_t)(m0 + wv * 32 + li) * D + quad * 8;
    const float* aptr1 = aptr0 + (size_t)16 * D;

    // B staging: waves 0,1 -> hi halves; waves 2,3 -> lo halves (8 KB each)
    const u16* gsrc = (wv < 2) ? Bph : Bpl;
    int soff = (wv & 1) * 4096;                      // u16 offset of this wave's half
    u16* l0 = ((wv < 2) ? Bh[0] : Bl[0]) + soff;
    u16* l1 = ((wv < 2) ? Bh[1] : Bl[1]) + soff;
    const u16* gb = gsrc + soff;

    f32x4 acc[2][16] = {};
    Areg rA, rB;

    auto stage = [&](u16* ldst, int k) {
        const u16* g = gb + (size_t)(ntb * 128 + k) * CHUNK + lane * 8;
        #pragma unroll
        for (int r = 0; r < 8; ++r)
            gl_lds16(g + r * 512, ldst + r * 512 + lane * 8);
    };

    auto computeStep = [&](const Areg& ar, const u16* BhBuf, const u16* BlBuf) {
        short8 ah[2], al[2];
        #pragma unroll
        for (int e = 0; e < 4; ++e) {
            u16 h, l;
            split_bf16(ar.a0lo[e], h, l); ah[0][e]     = (short)h; al[0][e]     = (short)l;
            split_bf16(ar.a0hi[e], h, l); ah[0][e + 4] = (short)h; al[0][e + 4] = (short)l;
            split_bf16(ar.a1lo[e], h, l); ah[1][e]     = (short)h; al[1][e]     = (short)l;
            split_bf16(ar.a1hi[e], h, l); ah[1][e + 4] = (short)h; al[1][e + 4] = (short)l;
        }
        #pragma unroll
        for (int ntl = 0; ntl < 16; ++ntl) {
            int off = quad * 2048 + (ntl * 16 + li) * 8;
            short8 bhf = *reinterpret_cast<const short8*>(BhBuf + off);
            short8 blf = *reinterpret_cast<const short8*>(BlBuf + off);
            #pragma unroll
            for (int mtl = 0; mtl < 2; ++mtl) {
                acc[mtl][ntl] = mfma16(ah[mtl], bhf, acc[mtl][ntl]);
                acc[mtl][ntl] = mfma16(al[mtl], bhf, acc[mtl][ntl]);
                acc[mtl][ntl] = mfma16(ah[mtl], blf, acc[mtl][ntl]);
            }
        }
    };

    // ---- prologue: stage step 0 into buf0, load A(0) ----
    stage(l0, 0);
    loadA(aptr0, aptr1, 0, rA);
    __syncthreads();

    for (int ks = 0; ks < KSTEPS; ks += 2) {
        int k1 = ks + 1;                                   // always < KSTEPS
        int k2 = (ks + 2 < KSTEPS) ? ks + 2 : KSTEPS - 1;  // clamp (last iter redundant)

        // ---- phase A: prefetch k1 -> {buf1, rB}; compute ks from {buf0, rA} ----
        stage(l1, k1);
        loadA(aptr0, aptr1, k1, rB);
        computeStep(rA, Bh[1 - 1], Bl[0]);                 // buf0
        __syncthreads();

        // ---- phase B: prefetch k2 -> {buf0, rA}; compute k1 from {buf1, rB} ----
        stage(l0, k2);
        loadA(aptr0, aptr1, k2, rA);
        computeStep(rB, Bh[1], Bl[1]);
        __syncthreads();
    }

    // ---- epilogue: +b1, exact GELU, *W2, reduce over this 256-wide n-slice ----
    float b1v[16], w2v[16];
    #pragma unroll
    for (int ntl = 0; ntl < 16; ++ntl) {
        b1v[ntl] = b1[n0 + ntl * 16 + li];
        w2v[ntl] = W2[n0 + ntl * 16 + li];
    }
    #pragma unroll
    for (int mtl = 0; mtl < 2; ++mtl) {
        #pragma unroll
        for (int r = 0; r < 4; ++r) {
            float s = 0.f;
            #pragma unroll
            for (int ntl = 0; ntl < 16; ++ntl) {
                float x = acc[mtl][ntl][r] + b1v[ntl];
                float g = 0.5f * x * (1.0f + erff(x * 0.70710678118654752f));
                s += g * w2v[ntl];
            }
            // reduce across the 16 lanes (li) of this quad
            s += __shfl_xor(s, 1, 64);
            s += __shfl_xor(s, 2, 64);
            s += __shfl_xor(s, 4, 64);
            s += __shfl_xor(s, 8, 64);
            if (li == 0) {
                int row = m0 + wv * 32 + mtl * 16 + quad * 4 + r;
                part[(size_t)ntb * M + row] = s;
            }
        }
    }
}

// ---------------------------------------------------------------------------
// Kernel B: per batch-row — reduce partials, sigmoid, variable-k selection
// via binary search over float-bit ordering. (verified; only NTB sum changed)
// ---------------------------------------------------------------------------
__global__ __launch_bounds__(256) void select_topk(
    const float* __restrict__ part,  // [NTB, M]
    const int*   __restrict__ mask,  // [BB, S] int32 (0/1)
    const float* __restrict__ b2,    // [1]
    float*       __restrict__ out)   // [2, BB, S]: weights then mask
{
    __shared__ unsigned us[S];
    __shared__ int      na_s, cnt_s, cgt_s, cge_s;
    __shared__ unsigned lo_s, hi_s;

    int brow = blockIdx.x;
    int tid  = threadIdx.x;

    if (tid == 0) na_s = 0;
    __syncthreads();

    float b2v = b2[0];
    int local_na = 0;
    for (int s = tid; s < S; s += 256) {
        float sum = 0.f;
        #pragma unroll
        for (int t = 0; t < NTB; ++t) sum += part[t * M + brow * S + s];
        float logit = sum + b2v;
        float sc = 1.0f / (1.0f + expf(-logit));
        int a = mask[brow * S + s];
        us[s] = a ? __float_as_uint(sc) : 0u;
        local_na += (a ? 1 : 0);
    }
    atomicAdd(&na_s, local_na);
    __syncthreads();

    int n_act = na_s;
    int k = (n_act >= 1) ? max(n_act >> 1, 1) : 0;

    unsigned T = 0;
    if (k > 0) {
        if (tid == 0) { lo_s = 1u; hi_s = 0x3F800000u; }
        __syncthreads();
        while (true) {
            unsigned lo = lo_s, hi = hi_s;
            if (lo >= hi) break;
            unsigned mid = lo + ((hi - lo + 1u) >> 1);
            int local = 0;
            for (int s = tid; s < S; s += 256) local += (us[s] >= mid) ? 1 : 0;
            if (tid == 0) cnt_s = 0;
            __syncthreads();
            #pragma unroll
            for (int off = 32; off > 0; off >>= 1)
                local += __shfl_down(local, off, 64);
            if ((tid & 63) == 0) atomicAdd(&cnt_s, local);
            __syncthreads();
            int c = cnt_s;
            if (tid == 0) { if (c >= k) lo_s = mid; else hi_s = mid - 1u; }
            __syncthreads();
        }
        T = lo_s;

        int lgt = 0, lge = 0;
        for (int s = tid; s < S; s += 256) {
            lgt += (us[s] > T) ? 1 : 0;
            lge += (us[s] >= T) ? 1 : 0;
        }
        if (tid == 0) { cgt_s = 0; cge_s = 0; }
        __syncthreads();
        #pragma unroll
        for (int off = 32; off > 0; off >>= 1) {
            lgt += __shfl_down(lgt, off, 64);
            lge += __shfl_down(lge, off, 64);
        }
        if ((tid & 63) == 0) { atomicAdd(&cgt_s, lgt); atomicAdd(&cge_s, lge); }
        __syncthreads();
        int c_gt = cgt_s, c_ge = cge_s;
        int need_eq = k - c_gt;
        if (c_ge - c_gt != need_eq) {
            if (tid == 0) {
                int taken = 0;
                for (int s = 0; s < S; ++s) {
                    if (us[s] == T) {
                        if (taken >= need_eq) us[s] = 0u;
                        ++taken;
                    }
                }
            }
            __syncthreads();
        }
    }
    __syncthreads();

    for (int s = tid; s < S; s += 256) {
        bool sel = (k > 0) && (us[s] >= T);
        float sc = __uint_as_float(us[s]);
        out[brow * S + s]     = sel ? sc : 0.0f;
        out[M + brow * S + s] = sel ? 1.0f : 0.0f;
    }
}

// ---------------------------------------------------------------------------
extern "C" void kernel_launch(void* const* d_in, const int* in_sizes, int n_in,
                              void* d_out, int out_size, void* d_ws, size_t ws_size,
                              hipStream_t stream)
{
    const float* X    = (const float*)d_in[0];  // hidden_states [8,4096,4096]
    const int*   mask = (const int*)  d_in[1];  // active_mask   [8,4096]
    const float* W1   = (const float*)d_in[2];  // [4096,1024]
    const float* b1   = (const float*)d_in[3];  // [1024]
    const float* W2   = (const float*)d_in[4];  // [1024,1]
    const float* b2   = (const float*)d_in[5];  // [1]
    float* out  = (float*)d_out;                // [2, 8, 4096]

    float* part = (float*)d_ws;                           // 512 KB used
    u16*   Bph  = (u16*)((char*)d_ws + (2u  << 20));      // 8 MB
    u16*   Bpl  = (u16*)((char*)d_ws + (10u << 20));      // 8 MB

    hipLaunchKernelGGL(pack_w1,   dim3(NTB * KSTEPS),  dim3(1024), 0, stream, W1, Bph, Bpl);
    hipLaunchKernelGGL(gemm_mfma, dim3(MTILES * NTB),  dim3(256),  0, stream,
                       X, Bph, Bpl, b1, W2, part);
    hipLaunchKernelGGL(select_topk, dim3(BB), dim3(256), 0, stream, part, mask, b2, out);
}